// Round 1
// baseline (1775.213 us; speedup 1.0000x reference)
//
#include <hip/hip_runtime.h>

#define D 64
#define NEG_SLOPE 0.01f

// ---------------------------------------------------------------------------
// Edge dtype detection: reference says int64, harness doc says int32.
// One wave inspects the first 128 int32 words: if every odd word is zero,
// the buffer is int64 (little-endian high words); random int32 src values
// in [0,1e5) make an all-zero odd pattern astronomically unlikely.
// ---------------------------------------------------------------------------
__global__ void detect_kernel(const void* __restrict__ ei, int* __restrict__ flag) {
    int lane = threadIdx.x & 63;
    const int* p = (const int*)ei;
    int v = p[2 * lane + 1];
    unsigned long long b = __ballot(v != 0);
    if (lane == 0) *flag = (b == 0ULL) ? 1 : 0;
}

__device__ __forceinline__ int edge_at(const void* __restrict__ ei, long long idx, int is64) {
    if (is64) return (int)((const long long*)ei)[idx];
    return ((const int*)ei)[idx];
}

// deg[d] += 1 for each edge (thread per edge, grid-stride)
__global__ void deg_kernel(const void* __restrict__ ei, long long E,
                           const int* __restrict__ flagp, float* __restrict__ deg) {
    int is64 = *flagp;
    long long tid = (long long)blockIdx.x * blockDim.x + threadIdx.x;
    long long nt = (long long)gridDim.x * blockDim.x;
    for (long long e = tid; e < E; e += nt) {
        int d = edge_at(ei, E + e, is64);
        atomicAdd(&deg[d], 1.0f);
    }
}

// invdeg[i] = 1 / max(deg[i], 1)   (in place over the deg buffer)
__global__ void invdeg_kernel(float* __restrict__ deg, int N) {
    int i = blockIdx.x * blockDim.x + threadIdx.x;
    if (i < N) deg[i] = 1.0f / fmaxf(deg[i], 1.0f);
}

// agg[dst][c] += h[src][c]; one wave per edge, lane = channel c.
// Gather and atomic scatter are both 256B contiguous per wave.
__global__ void agg_kernel(const float* __restrict__ h, const void* __restrict__ ei,
                           const int* __restrict__ flagp, long long E,
                           float* __restrict__ agg) {
    int is64 = *flagp;
    int lane = threadIdx.x & 63;
    long long wid = (long long)blockIdx.x * (blockDim.x >> 6) + (threadIdx.x >> 6);
    long long nw = (long long)gridDim.x * (blockDim.x >> 6);
    for (long long e = wid; e < E; e += nw) {
        int s = edge_at(ei, e, is64);
        int d = edge_at(ei, E + e, is64);
        atomicAdd(&agg[(long long)d * D + lane], h[(long long)s * D + lane]);
    }
}

// io holds agg on entry, h_next on exit (in-place, each wave owns its rows).
// y[c] = leaky( b[c] + sum_k Wl[c][k]*mean[k] + Wr[c][k]*x[k] )
// Weights staged transposed in LDS with stride 65 -> conflict-free reads
// (lane c reads sW[k*65+c], consecutive addresses). mean[k]/x[k] broadcast
// via __shfl (no cross-wave LDS, no barriers in the loop).
__global__ __launch_bounds__(256) void transform_kernel(
        float* __restrict__ io, const float* __restrict__ hin,
        const float* __restrict__ invd,
        const float* __restrict__ Wl, const float* __restrict__ bl,
        const float* __restrict__ Wr, int N) {
    __shared__ float sWl[64 * 65];
    __shared__ float sWr[64 * 65];
    for (int i = threadIdx.x; i < 64 * 64; i += blockDim.x) {
        int c = i >> 6, k = i & 63;
        sWl[k * 65 + c] = Wl[i];
        sWr[k * 65 + c] = Wr[i];
    }
    __syncthreads();

    int lane = threadIdx.x & 63;
    int wid = blockIdx.x * (blockDim.x >> 6) + (threadIdx.x >> 6);
    int nw = gridDim.x * (blockDim.x >> 6);
    float bias = bl[lane];
    for (int i = wid; i < N; i += nw) {
        float m = io[(long long)i * D + lane] * invd[i];
        float x = hin[(long long)i * D + lane];
        float y = bias;
#pragma unroll
        for (int k = 0; k < 64; ++k) {
            float mk = __shfl(m, k, 64);
            float xk = __shfl(x, k, 64);
            y += sWl[k * 65 + lane] * mk + sWr[k * 65 + lane] * xk;
        }
        y = (y >= 0.0f) ? y : NEG_SLOPE * y;
        io[(long long)i * D + lane] = y;
    }
}

// out[i] = b_out + sum_k h[i][k] * W_out[k]   (wave per node, shuffle reduce)
__global__ void out_kernel(const float* __restrict__ h, const float* __restrict__ Wout,
                           const float* __restrict__ bout, float* __restrict__ out, int N) {
    int lane = threadIdx.x & 63;
    int wid = blockIdx.x * (blockDim.x >> 6) + (threadIdx.x >> 6);
    int nw = gridDim.x * (blockDim.x >> 6);
    float w = Wout[lane];
    float b = bout[0];
    for (int i = wid; i < N; i += nw) {
        float v = h[(long long)i * D + lane] * w;
#pragma unroll
        for (int off = 32; off > 0; off >>= 1) v += __shfl_xor(v, off, 64);
        if (lane == 0) out[i] = v + b;
    }
}

extern "C" void kernel_launch(void* const* d_in, const int* in_sizes, int n_in,
                              void* d_out, int out_size, void* d_ws, size_t ws_size,
                              hipStream_t stream) {
    const float* x    = (const float*)d_in[0];
    const void*  ei   = d_in[1];
    const float* Wl1  = (const float*)d_in[2];
    const float* bl1  = (const float*)d_in[3];
    const float* Wr1  = (const float*)d_in[4];
    const float* Wl2  = (const float*)d_in[5];
    const float* bl2  = (const float*)d_in[6];
    const float* Wr2  = (const float*)d_in[7];
    const float* Wl3  = (const float*)d_in[8];
    const float* bl3  = (const float*)d_in[9];
    const float* Wr3  = (const float*)d_in[10];
    const float* Wout = (const float*)d_in[11];
    const float* bout = (const float*)d_in[12];
    float* out = (float*)d_out;

    int       N = in_sizes[0] / D;
    long long E = (long long)in_sizes[1] / 2;

    // workspace layout
    char* ws = (char*)d_ws;
    int* flag = (int*)ws;                                  // 256 B
    float* invd = (float*)(ws + 256);                      // N floats
    size_t off = 256 + (((size_t)N * 4 + 255) / 256) * 256;
    float* bufA = (float*)(ws + off); off += (size_t)N * D * 4;
    float* bufB = (float*)(ws + off);

    const size_t featBytes = (size_t)N * D * sizeof(float);

    detect_kernel<<<1, 64, 0, stream>>>(ei, flag);

    // degree -> invdeg (layer-invariant)
    hipMemsetAsync(invd, 0, (size_t)N * sizeof(float), stream);
    deg_kernel<<<2048, 256, 0, stream>>>(ei, E, flag, invd);
    invdeg_kernel<<<(N + 255) / 256, 256, 0, stream>>>(invd, N);

    // layer 1: x -> bufA
    hipMemsetAsync(bufA, 0, featBytes, stream);
    agg_kernel<<<2048, 256, 0, stream>>>(x, ei, flag, E, bufA);
    transform_kernel<<<1024, 256, 0, stream>>>(bufA, x, invd, Wl1, bl1, Wr1, N);

    // layer 2: bufA -> bufB
    hipMemsetAsync(bufB, 0, featBytes, stream);
    agg_kernel<<<2048, 256, 0, stream>>>(bufA, ei, flag, E, bufB);
    transform_kernel<<<1024, 256, 0, stream>>>(bufB, bufA, invd, Wl2, bl2, Wr2, N);

    // layer 3: bufB -> bufA
    hipMemsetAsync(bufA, 0, featBytes, stream);
    agg_kernel<<<2048, 256, 0, stream>>>(bufB, ei, flag, E, bufA);
    transform_kernel<<<1024, 256, 0, stream>>>(bufA, bufB, invd, Wl3, bl3, Wr3, N);

    // head
    out_kernel<<<1024, 256, 0, stream>>>(bufA, Wout, bout, out, N);
}

// Round 2
// 1045.280 us; speedup vs baseline: 1.6983x; 1.6983x over previous
//
#include <hip/hip_runtime.h>

#define D 64
#define NEG_SLOPE 0.01f
#define SCAN_BLOCK 256
#define SCAN_ITEMS 4   // elements per thread -> 1024 per block

// ---------------------------------------------------------------------------
// Edge dtype detection: reference says int64, harness may hand int32.
// One wave inspects the first 128 int32 words: if every odd word is zero,
// the buffer is int64 (little-endian high words).
// ---------------------------------------------------------------------------
__global__ void detect_kernel(const void* __restrict__ ei, int* __restrict__ flag) {
    int lane = threadIdx.x & 63;
    const int* p = (const int*)ei;
    int v = p[2 * lane + 1];
    unsigned long long b = __ballot(v != 0);
    if (lane == 0) *flag = (b == 0ULL) ? 1 : 0;
}

__device__ __forceinline__ int edge_at(const void* __restrict__ ei, long long idx, int is64) {
    if (is64) return (int)((const long long*)ei)[idx];
    return ((const int*)ei)[idx];
}

// histogram of dst into rowptr[0..N-1] (int32 atomics)
__global__ void count_kernel(const void* __restrict__ ei, long long E,
                             const int* __restrict__ flagp, int* __restrict__ rowptr) {
    int is64 = *flagp;
    long long tid = (long long)blockIdx.x * blockDim.x + threadIdx.x;
    long long nt = (long long)gridDim.x * blockDim.x;
    for (long long e = tid; e < E; e += nt) {
        int d = edge_at(ei, E + e, is64);
        atomicAdd(&rowptr[d], 1);
    }
}

// ---- 3-kernel exclusive scan over rowptr[0..N-1], in place ----
__global__ void scan1_kernel(int* __restrict__ data, int* __restrict__ blockSums, int N) {
    __shared__ int s[SCAN_BLOCK];
    int base = blockIdx.x * (SCAN_BLOCK * SCAN_ITEMS);
    int t = threadIdx.x;
    int v[SCAN_ITEMS];
    int sum = 0;
#pragma unroll
    for (int j = 0; j < SCAN_ITEMS; ++j) {
        int idx = base + t * SCAN_ITEMS + j;
        v[j] = (idx < N) ? data[idx] : 0;
        sum += v[j];
    }
    s[t] = sum;
    __syncthreads();
    for (int off = 1; off < SCAN_BLOCK; off <<= 1) {
        int val = (t >= off) ? s[t - off] : 0;
        __syncthreads();
        s[t] += val;
        __syncthreads();
    }
    if (t == SCAN_BLOCK - 1) blockSums[blockIdx.x] = s[t];
    int run = s[t] - sum;  // exclusive prefix of this thread's chunk
#pragma unroll
    for (int j = 0; j < SCAN_ITEMS; ++j) {
        int idx = base + t * SCAN_ITEMS + j;
        if (idx < N) data[idx] = run;
        run += v[j];
    }
}

__global__ void scan2_kernel(int* __restrict__ blockSums, int nb) {
    __shared__ int s[SCAN_BLOCK];
    int t = threadIdx.x;
    int v = (t < nb) ? blockSums[t] : 0;
    s[t] = v;
    __syncthreads();
    for (int off = 1; off < SCAN_BLOCK; off <<= 1) {
        int val = (t >= off) ? s[t - off] : 0;
        __syncthreads();
        s[t] += val;
        __syncthreads();
    }
    if (t < nb) blockSums[t] = s[t] - v;  // exclusive
}

__global__ void scan3_kernel(int* __restrict__ rowptr, const int* __restrict__ blockSums,
                             int N, int E) {
    int idx = blockIdx.x * blockDim.x + threadIdx.x;
    if (idx < N) rowptr[idx] += blockSums[idx / (SCAN_BLOCK * SCAN_ITEMS)];
    if (idx == N) rowptr[N] = E;
}

__global__ void cursor_init_kernel(int* __restrict__ cursor, const int* __restrict__ rowptr, int N) {
    int i = blockIdx.x * blockDim.x + threadIdx.x;
    if (i < N) cursor[i] = rowptr[i];
}

// adj[pos] = src, pos handed out by per-dst atomic ticket
__global__ void fill_kernel(const void* __restrict__ ei, long long E,
                            const int* __restrict__ flagp,
                            int* __restrict__ cursor, int* __restrict__ adj) {
    int is64 = *flagp;
    long long tid = (long long)blockIdx.x * blockDim.x + threadIdx.x;
    long long nt = (long long)gridDim.x * blockDim.x;
    for (long long e = tid; e < E; e += nt) {
        int s = edge_at(ei, e, is64);
        int d = edge_at(ei, E + e, is64);
        int pos = atomicAdd(&cursor[d], 1);
        adj[pos] = s;
    }
}

// ---------------------------------------------------------------------------
// Fused layer: wave per node. Sum neighbor rows via CSR gather (256B coalesced
// per row), mean via degree from rowptr, then y = leaky(b + Wl*mean + Wr*x).
// Weights transposed in LDS with stride 65 (conflict-free); mean/x broadcast
// via shfl. hout[i] written once by its owning wave.
// ---------------------------------------------------------------------------
__global__ __launch_bounds__(256) void layer_kernel(
        const float* __restrict__ hin, const int* __restrict__ rowptr,
        const int* __restrict__ adj,
        const float* __restrict__ Wl, const float* __restrict__ bl,
        const float* __restrict__ Wr,
        float* __restrict__ hout, int N) {
    __shared__ float sWl[64 * 65];
    __shared__ float sWr[64 * 65];
    for (int i = threadIdx.x; i < 64 * 64; i += blockDim.x) {
        int c = i >> 6, k = i & 63;
        sWl[k * 65 + c] = Wl[i];
        sWr[k * 65 + c] = Wr[i];
    }
    __syncthreads();

    int lane = threadIdx.x & 63;
    int wid = blockIdx.x * (blockDim.x >> 6) + (threadIdx.x >> 6);
    int nw = gridDim.x * (blockDim.x >> 6);
    float bias = bl[lane];

    for (int i = wid; i < N; i += nw) {
        int b0 = rowptr[i], b1 = rowptr[i + 1];
        float acc = 0.0f;
        for (int base = b0; base < b1; base += 64) {
            int idx = base + lane;
            int sl = (idx < b1) ? adj[idx] : 0;  // coalesced adj chunk
            int cnt = min(64, b1 - base);
            int j = 0;
            for (; j + 4 <= cnt; j += 4) {       // 4 gathers in flight
                int s0 = __shfl(sl, j, 64);
                int s1 = __shfl(sl, j + 1, 64);
                int s2 = __shfl(sl, j + 2, 64);
                int s3 = __shfl(sl, j + 3, 64);
                float v0 = hin[(long long)s0 * D + lane];
                float v1 = hin[(long long)s1 * D + lane];
                float v2 = hin[(long long)s2 * D + lane];
                float v3 = hin[(long long)s3 * D + lane];
                acc += (v0 + v1) + (v2 + v3);
            }
            for (; j < cnt; ++j) {
                int s = __shfl(sl, j, 64);
                acc += hin[(long long)s * D + lane];
            }
        }
        float deg = (float)(b1 - b0);
        float m = acc * (1.0f / fmaxf(deg, 1.0f));
        float x = hin[(long long)i * D + lane];
        float y = bias;
#pragma unroll
        for (int k = 0; k < 64; ++k) {
            float mk = __shfl(m, k, 64);
            float xk = __shfl(x, k, 64);
            y += sWl[k * 65 + lane] * mk + sWr[k * 65 + lane] * xk;
        }
        y = (y >= 0.0f) ? y : NEG_SLOPE * y;
        hout[(long long)i * D + lane] = y;
    }
}

// out[i] = b_out + sum_k h[i][k] * W_out[k]   (wave per node, shuffle reduce)
__global__ void out_kernel(const float* __restrict__ h, const float* __restrict__ Wout,
                           const float* __restrict__ bout, float* __restrict__ out, int N) {
    int lane = threadIdx.x & 63;
    int wid = blockIdx.x * (blockDim.x >> 6) + (threadIdx.x >> 6);
    int nw = gridDim.x * (blockDim.x >> 6);
    float w = Wout[lane];
    float b = bout[0];
    for (int i = wid; i < N; i += nw) {
        float v = h[(long long)i * D + lane] * w;
#pragma unroll
        for (int off = 32; off > 0; off >>= 1) v += __shfl_xor(v, off, 64);
        if (lane == 0) out[i] = v + b;
    }
}

extern "C" void kernel_launch(void* const* d_in, const int* in_sizes, int n_in,
                              void* d_out, int out_size, void* d_ws, size_t ws_size,
                              hipStream_t stream) {
    const float* x    = (const float*)d_in[0];
    const void*  ei   = d_in[1];
    const float* Wl1  = (const float*)d_in[2];
    const float* bl1  = (const float*)d_in[3];
    const float* Wr1  = (const float*)d_in[4];
    const float* Wl2  = (const float*)d_in[5];
    const float* bl2  = (const float*)d_in[6];
    const float* Wr2  = (const float*)d_in[7];
    const float* Wl3  = (const float*)d_in[8];
    const float* bl3  = (const float*)d_in[9];
    const float* Wr3  = (const float*)d_in[10];
    const float* Wout = (const float*)d_in[11];
    const float* bout = (const float*)d_in[12];
    float* out = (float*)d_out;

    int       N = in_sizes[0] / D;
    long long E = (long long)in_sizes[1] / 2;

    // workspace layout
    char* ws = (char*)d_ws;
    int* flag = (int*)ws;                                       // 256 B
    size_t off = 256;
    int* rowptr = (int*)(ws + off); off += (((size_t)(N + 1) * 4 + 255) / 256) * 256;
    int* blockSums = (int*)(ws + off); off += 4096;             // up to 1024 blocks
    int* adj = (int*)(ws + off); off += (((size_t)E * 4 + 255) / 256) * 256;
    float* bufA = (float*)(ws + off); off += (size_t)N * D * 4;
    float* bufB = (float*)(ws + off);
    int* cursor = (int*)bufB;  // bufB not live until layer 2; stream-ordered => safe

    detect_kernel<<<1, 64, 0, stream>>>(ei, flag);

    // ---- CSR build (once; graph is layer-invariant) ----
    hipMemsetAsync(rowptr, 0, (size_t)(N + 1) * sizeof(int), stream);
    count_kernel<<<2048, 256, 0, stream>>>(ei, E, flag, rowptr);
    int nb = (N + SCAN_BLOCK * SCAN_ITEMS - 1) / (SCAN_BLOCK * SCAN_ITEMS);
    scan1_kernel<<<nb, SCAN_BLOCK, 0, stream>>>(rowptr, blockSums, N);
    scan2_kernel<<<1, SCAN_BLOCK, 0, stream>>>(blockSums, nb);
    scan3_kernel<<<(N + 256) / 256, 256, 0, stream>>>(rowptr, blockSums, N, (int)E);
    cursor_init_kernel<<<(N + 255) / 256, 256, 0, stream>>>(cursor, rowptr, N);
    fill_kernel<<<2048, 256, 0, stream>>>(ei, E, flag, cursor, adj);

    // ---- 3 fused SAGE layers ----
    layer_kernel<<<2048, 256, 0, stream>>>(x,    rowptr, adj, Wl1, bl1, Wr1, bufA, N);
    layer_kernel<<<2048, 256, 0, stream>>>(bufA, rowptr, adj, Wl2, bl2, Wr2, bufB, N);
    layer_kernel<<<2048, 256, 0, stream>>>(bufB, rowptr, adj, Wl3, bl3, Wr3, bufA, N);

    // ---- head ----
    out_kernel<<<1024, 256, 0, stream>>>(bufA, Wout, bout, out, N);
}

// Round 3
// 941.908 us; speedup vs baseline: 1.8847x; 1.1097x over previous
//
#include <hip/hip_runtime.h>

#define D 64
#define NEG_SLOPE 0.01f
#define SCAN_BLOCK 256
#define SCAN_ITEMS 4   // elements per thread -> 1024 per block

// ---------------------------------------------------------------------------
// Edge dtype detection: reference says int64, harness may hand int32.
// ---------------------------------------------------------------------------
__global__ void detect_kernel(const void* __restrict__ ei, int* __restrict__ flag) {
    int lane = threadIdx.x & 63;
    const int* p = (const int*)ei;
    int v = p[2 * lane + 1];
    unsigned long long b = __ballot(v != 0);
    if (lane == 0) *flag = (b == 0ULL) ? 1 : 0;
}

__device__ __forceinline__ int edge_at(const void* __restrict__ ei, long long idx, int is64) {
    if (is64) return (int)((const long long*)ei)[idx];
    return ((const int*)ei)[idx];
}

// histogram of dst into rowptr[0..N-1]
__global__ void count_kernel(const void* __restrict__ ei, long long E,
                             const int* __restrict__ flagp, int* __restrict__ rowptr) {
    int is64 = *flagp;
    long long tid = (long long)blockIdx.x * blockDim.x + threadIdx.x;
    long long nt = (long long)gridDim.x * blockDim.x;
    for (long long e = tid; e < E; e += nt) {
        int d = edge_at(ei, E + e, is64);
        atomicAdd(&rowptr[d], 1);
    }
}

// ---- 3-kernel exclusive scan over rowptr[0..N-1], in place ----
__global__ void scan1_kernel(int* __restrict__ data, int* __restrict__ blockSums, int N) {
    __shared__ int s[SCAN_BLOCK];
    int base = blockIdx.x * (SCAN_BLOCK * SCAN_ITEMS);
    int t = threadIdx.x;
    int v[SCAN_ITEMS];
    int sum = 0;
#pragma unroll
    for (int j = 0; j < SCAN_ITEMS; ++j) {
        int idx = base + t * SCAN_ITEMS + j;
        v[j] = (idx < N) ? data[idx] : 0;
        sum += v[j];
    }
    s[t] = sum;
    __syncthreads();
    for (int off = 1; off < SCAN_BLOCK; off <<= 1) {
        int val = (t >= off) ? s[t - off] : 0;
        __syncthreads();
        s[t] += val;
        __syncthreads();
    }
    if (t == SCAN_BLOCK - 1) blockSums[blockIdx.x] = s[t];
    int run = s[t] - sum;
#pragma unroll
    for (int j = 0; j < SCAN_ITEMS; ++j) {
        int idx = base + t * SCAN_ITEMS + j;
        if (idx < N) data[idx] = run;
        run += v[j];
    }
}

__global__ void scan2_kernel(int* __restrict__ blockSums, int nb) {
    __shared__ int s[SCAN_BLOCK];
    int t = threadIdx.x;
    int v = (t < nb) ? blockSums[t] : 0;
    s[t] = v;
    __syncthreads();
    for (int off = 1; off < SCAN_BLOCK; off <<= 1) {
        int val = (t >= off) ? s[t - off] : 0;
        __syncthreads();
        s[t] += val;
        __syncthreads();
    }
    if (t < nb) blockSums[t] = s[t] - v;
}

__global__ void scan3_kernel(int* __restrict__ rowptr, const int* __restrict__ blockSums,
                             int N, int E) {
    int idx = blockIdx.x * blockDim.x + threadIdx.x;
    if (idx < N) rowptr[idx] += blockSums[idx / (SCAN_BLOCK * SCAN_ITEMS)];
    if (idx == N) rowptr[N] = E;
}

__global__ void cursor_init_kernel(int* __restrict__ cursor, const int* __restrict__ rowptr, int N) {
    int i = blockIdx.x * blockDim.x + threadIdx.x;
    if (i < N) cursor[i] = rowptr[i];
}

__global__ void fill_kernel(const void* __restrict__ ei, long long E,
                            const int* __restrict__ flagp,
                            int* __restrict__ cursor, int* __restrict__ adj) {
    int is64 = *flagp;
    long long tid = (long long)blockIdx.x * blockDim.x + threadIdx.x;
    long long nt = (long long)gridDim.x * blockDim.x;
    for (long long e = tid; e < E; e += nt) {
        int s = edge_at(ei, e, is64);
        int d = edge_at(ei, E + e, is64);
        int pos = atomicAdd(&cursor[d], 1);
        adj[pos] = s;
    }
}

// ---------------------------------------------------------------------------
// Gather+mean: wave per node. 16 lanes per neighbor row (float4/lane), so one
// load instruction covers 4 rows (1 KB/wave); unroll 4 -> 16 rows in flight.
// Partials reduced across the 4 lane-groups with two shfl_xor. No LDS, low
// VGPR -> high occupancy for latency hiding.
// ---------------------------------------------------------------------------
__global__ __launch_bounds__(256) void agg_kernel(
        const float* __restrict__ hin, const int* __restrict__ rowptr,
        const int* __restrict__ adj, float* __restrict__ mout, int N) {
    int lane = threadIdx.x & 63;
    int sub = lane & 15;      // float4 slot within row
    int grp = lane >> 4;      // which of 4 concurrent rows
    int wid = blockIdx.x * (blockDim.x >> 6) + (threadIdx.x >> 6);
    int nw = gridDim.x * (blockDim.x >> 6);

    for (int i = wid; i < N; i += nw) {
        int b0 = rowptr[i], b1 = rowptr[i + 1];
        float ax = 0.f, ay = 0.f, az = 0.f, aw = 0.f;
        for (int base = b0; base < b1; base += 64) {
            int idx = base + lane;
            int sl = (idx < b1) ? adj[idx] : 0;   // coalesced adj chunk
            int cnt = min(64, b1 - base);
            int nq = (cnt + 3) >> 2;
#pragma unroll 4
            for (int t = 0; t < nq; ++t) {
                int j = (t << 2) + grp;
                int s = __shfl(sl, j, 64);
                if (j < cnt) {
                    const float4 v = *(const float4*)(hin + (size_t)s * D + (sub << 2));
                    ax += v.x; ay += v.y; az += v.z; aw += v.w;
                }
            }
        }
        // reduce partials across the 4 lane-groups
        ax += __shfl_xor(ax, 16, 64); ay += __shfl_xor(ay, 16, 64);
        az += __shfl_xor(az, 16, 64); aw += __shfl_xor(aw, 16, 64);
        ax += __shfl_xor(ax, 32, 64); ay += __shfl_xor(ay, 32, 64);
        az += __shfl_xor(az, 32, 64); aw += __shfl_xor(aw, 32, 64);
        if (grp == 0) {
            float inv = 1.0f / fmaxf((float)(b1 - b0), 1.0f);
            float4 r = make_float4(ax * inv, ay * inv, az * inv, aw * inv);
            *(float4*)(mout + (size_t)i * D + (sub << 2)) = r;
        }
    }
}

// ---------------------------------------------------------------------------
// Transform: wave per node, lane = out channel. mean read (and overwritten)
// in-place; weights transposed in LDS stride-65. If final!=0, fuse the output
// head: out[i] = b_out + Wout . y  (no hout write at all).
// ---------------------------------------------------------------------------
__global__ __launch_bounds__(256) void transform_kernel(
        float* __restrict__ mean, const float* __restrict__ hin,
        const float* __restrict__ Wl, const float* __restrict__ bl,
        const float* __restrict__ Wr,
        const float* __restrict__ Wout, const float* __restrict__ bout,
        float* __restrict__ out, int N, int final_flag) {
    __shared__ float sWl[64 * 65];
    __shared__ float sWr[64 * 65];
    for (int i = threadIdx.x; i < 64 * 64; i += blockDim.x) {
        int c = i >> 6, k = i & 63;
        sWl[k * 65 + c] = Wl[i];
        sWr[k * 65 + c] = Wr[i];
    }
    __syncthreads();

    int lane = threadIdx.x & 63;
    int wid = blockIdx.x * (blockDim.x >> 6) + (threadIdx.x >> 6);
    int nw = gridDim.x * (blockDim.x >> 6);
    float bias = bl[lane];
    float wo = final_flag ? Wout[lane] : 0.0f;
    float bo = final_flag ? bout[0] : 0.0f;

    for (int i = wid; i < N; i += nw) {
        float m = mean[(size_t)i * D + lane];
        float x = hin[(size_t)i * D + lane];
        float y = bias;
#pragma unroll
        for (int k = 0; k < 64; ++k) {
            float mk = __shfl(m, k, 64);
            float xk = __shfl(x, k, 64);
            y += sWl[k * 65 + lane] * mk + sWr[k * 65 + lane] * xk;
        }
        y = (y >= 0.0f) ? y : NEG_SLOPE * y;
        if (final_flag) {
            float v = y * wo;
#pragma unroll
            for (int off = 32; off > 0; off >>= 1) v += __shfl_xor(v, off, 64);
            if (lane == 0) out[i] = v + bo;
        } else {
            mean[(size_t)i * D + lane] = y;   // in-place: wave owns row i
        }
    }
}

extern "C" void kernel_launch(void* const* d_in, const int* in_sizes, int n_in,
                              void* d_out, int out_size, void* d_ws, size_t ws_size,
                              hipStream_t stream) {
    const float* x    = (const float*)d_in[0];
    const void*  ei   = d_in[1];
    const float* Wl1  = (const float*)d_in[2];
    const float* bl1  = (const float*)d_in[3];
    const float* Wr1  = (const float*)d_in[4];
    const float* Wl2  = (const float*)d_in[5];
    const float* bl2  = (const float*)d_in[6];
    const float* Wr2  = (const float*)d_in[7];
    const float* Wl3  = (const float*)d_in[8];
    const float* bl3  = (const float*)d_in[9];
    const float* Wr3  = (const float*)d_in[10];
    const float* Wout = (const float*)d_in[11];
    const float* bout = (const float*)d_in[12];
    float* out = (float*)d_out;

    int       N = in_sizes[0] / D;
    long long E = (long long)in_sizes[1] / 2;

    // workspace layout
    char* ws = (char*)d_ws;
    int* flag = (int*)ws;
    size_t off = 256;
    int* rowptr = (int*)(ws + off); off += (((size_t)(N + 1) * 4 + 255) / 256) * 256;
    int* blockSums = (int*)(ws + off); off += 4096;
    int* adj = (int*)(ws + off); off += (((size_t)E * 4 + 255) / 256) * 256;
    float* bufA = (float*)(ws + off); off += (size_t)N * D * 4;
    float* bufB = (float*)(ws + off);
    int* cursor = (int*)bufB;  // bufB not live until layer-2 agg; stream order => safe

    detect_kernel<<<1, 64, 0, stream>>>(ei, flag);

    // ---- CSR build (once; graph is layer-invariant) ----
    hipMemsetAsync(rowptr, 0, (size_t)(N + 1) * sizeof(int), stream);
    count_kernel<<<2048, 256, 0, stream>>>(ei, E, flag, rowptr);
    int nb = (N + SCAN_BLOCK * SCAN_ITEMS - 1) / (SCAN_BLOCK * SCAN_ITEMS);
    scan1_kernel<<<nb, SCAN_BLOCK, 0, stream>>>(rowptr, blockSums, N);
    scan2_kernel<<<1, SCAN_BLOCK, 0, stream>>>(blockSums, nb);
    scan3_kernel<<<(N + 256) / 256, 256, 0, stream>>>(rowptr, blockSums, N, (int)E);
    cursor_init_kernel<<<(N + 255) / 256, 256, 0, stream>>>(cursor, rowptr, N);
    fill_kernel<<<2048, 256, 0, stream>>>(ei, E, flag, cursor, adj);

    // ---- layer 1: x -> bufA ----
    agg_kernel<<<4096, 256, 0, stream>>>(x, rowptr, adj, bufA, N);
    transform_kernel<<<2048, 256, 0, stream>>>(bufA, x, Wl1, bl1, Wr1,
                                               Wout, bout, out, N, 0);
    // ---- layer 2: bufA -> bufB ----
    agg_kernel<<<4096, 256, 0, stream>>>(bufA, rowptr, adj, bufB, N);
    transform_kernel<<<2048, 256, 0, stream>>>(bufB, bufA, Wl2, bl2, Wr2,
                                               Wout, bout, out, N, 0);
    // ---- layer 3 + fused head: bufB -> out ----
    agg_kernel<<<4096, 256, 0, stream>>>(bufB, rowptr, adj, bufA, N);
    transform_kernel<<<2048, 256, 0, stream>>>(bufA, bufB, Wl3, bl3, Wr3,
                                               Wout, bout, out, N, 1);
}

// Round 4
// 581.228 us; speedup vs baseline: 3.0542x; 1.6205x over previous
//
#include <hip/hip_runtime.h>

#define D 64
#define NEG_SLOPE 0.01f
#define SCAN_BLOCK 256
#define SCAN_ITEMS 4   // elements per thread -> 1024 per block
#define SA_STRIDE 132  // 128 nodes + 4 pad (k-major tile), mod 32 = 4 -> 2-way max
#define SW_STRIDE 68   // 64 ch + 4 pad

// ---------------------------------------------------------------------------
// Edge dtype detection: reference says int64, harness may hand int32.
// ---------------------------------------------------------------------------
__global__ void detect_kernel(const void* __restrict__ ei, int* __restrict__ flag) {
    int lane = threadIdx.x & 63;
    const int* p = (const int*)ei;
    int v = p[2 * lane + 1];
    unsigned long long b = __ballot(v != 0);
    if (lane == 0) *flag = (b == 0ULL) ? 1 : 0;
}

__device__ __forceinline__ int edge_at(const void* __restrict__ ei, long long idx, int is64) {
    if (is64) return (int)((const long long*)ei)[idx];
    return ((const int*)ei)[idx];
}

// histogram of dst into rowptr[0..N-1]
__global__ void count_kernel(const void* __restrict__ ei, long long E,
                             const int* __restrict__ flagp, int* __restrict__ rowptr) {
    int is64 = *flagp;
    long long tid = (long long)blockIdx.x * blockDim.x + threadIdx.x;
    long long nt = (long long)gridDim.x * blockDim.x;
    for (long long e = tid; e < E; e += nt) {
        int d = edge_at(ei, E + e, is64);
        atomicAdd(&rowptr[d], 1);
    }
}

// ---- 3-kernel exclusive scan over rowptr[0..N-1], in place ----
__global__ void scan1_kernel(int* __restrict__ data, int* __restrict__ blockSums, int N) {
    __shared__ int s[SCAN_BLOCK];
    int base = blockIdx.x * (SCAN_BLOCK * SCAN_ITEMS);
    int t = threadIdx.x;
    int v[SCAN_ITEMS];
    int sum = 0;
#pragma unroll
    for (int j = 0; j < SCAN_ITEMS; ++j) {
        int idx = base + t * SCAN_ITEMS + j;
        v[j] = (idx < N) ? data[idx] : 0;
        sum += v[j];
    }
    s[t] = sum;
    __syncthreads();
    for (int off = 1; off < SCAN_BLOCK; off <<= 1) {
        int val = (t >= off) ? s[t - off] : 0;
        __syncthreads();
        s[t] += val;
        __syncthreads();
    }
    if (t == SCAN_BLOCK - 1) blockSums[blockIdx.x] = s[t];
    int run = s[t] - sum;
#pragma unroll
    for (int j = 0; j < SCAN_ITEMS; ++j) {
        int idx = base + t * SCAN_ITEMS + j;
        if (idx < N) data[idx] = run;
        run += v[j];
    }
}

__global__ void scan2_kernel(int* __restrict__ blockSums, int nb) {
    __shared__ int s[SCAN_BLOCK];
    int t = threadIdx.x;
    int v = (t < nb) ? blockSums[t] : 0;
    s[t] = v;
    __syncthreads();
    for (int off = 1; off < SCAN_BLOCK; off <<= 1) {
        int val = (t >= off) ? s[t - off] : 0;
        __syncthreads();
        s[t] += val;
        __syncthreads();
    }
    if (t < nb) blockSums[t] = s[t] - v;
}

__global__ void scan3_kernel(int* __restrict__ rowptr, const int* __restrict__ blockSums,
                             int N, int E) {
    int idx = blockIdx.x * blockDim.x + threadIdx.x;
    if (idx < N) rowptr[idx] += blockSums[idx / (SCAN_BLOCK * SCAN_ITEMS)];
    if (idx == N) rowptr[N] = E;
}

__global__ void cursor_init_kernel(int* __restrict__ cursor, const int* __restrict__ rowptr, int N) {
    int i = blockIdx.x * blockDim.x + threadIdx.x;
    if (i < N) cursor[i] = rowptr[i];
}

__global__ void fill_kernel(const void* __restrict__ ei, long long E,
                            const int* __restrict__ flagp,
                            int* __restrict__ cursor, int* __restrict__ adj) {
    int is64 = *flagp;
    long long tid = (long long)blockIdx.x * blockDim.x + threadIdx.x;
    long long nt = (long long)gridDim.x * blockDim.x;
    for (long long e = tid; e < E; e += nt) {
        int s = edge_at(ei, e, is64);
        int d = edge_at(ei, E + e, is64);
        int pos = atomicAdd(&cursor[d], 1);
        adj[pos] = s;
    }
}

// ---------------------------------------------------------------------------
// Gather+mean: wave per node. 16 lanes per neighbor row (float4/lane), so one
// load instruction covers 4 rows (1 KB/wave); unroll 4 -> 16 rows in flight.
// ---------------------------------------------------------------------------
__global__ __launch_bounds__(256) void agg_kernel(
        const float* __restrict__ hin, const int* __restrict__ rowptr,
        const int* __restrict__ adj, float* __restrict__ mout, int N) {
    int lane = threadIdx.x & 63;
    int sub = lane & 15;      // float4 slot within row
    int grp = lane >> 4;      // which of 4 concurrent rows
    int wid = blockIdx.x * (blockDim.x >> 6) + (threadIdx.x >> 6);
    int nw = gridDim.x * (blockDim.x >> 6);

    for (int i = wid; i < N; i += nw) {
        int b0 = rowptr[i], b1 = rowptr[i + 1];
        float ax = 0.f, ay = 0.f, az = 0.f, aw = 0.f;
        for (int base = b0; base < b1; base += 64) {
            int idx = base + lane;
            int sl = (idx < b1) ? adj[idx] : 0;   // coalesced adj chunk
            int cnt = min(64, b1 - base);
            int nq = (cnt + 3) >> 2;
#pragma unroll 4
            for (int t = 0; t < nq; ++t) {
                int j = (t << 2) + grp;
                int s = __shfl(sl, j, 64);
                if (j < cnt) {
                    const float4 v = *(const float4*)(hin + (size_t)s * D + (sub << 2));
                    ax += v.x; ay += v.y; az += v.z; aw += v.w;
                }
            }
        }
        ax += __shfl_xor(ax, 16, 64); ay += __shfl_xor(ay, 16, 64);
        az += __shfl_xor(az, 16, 64); aw += __shfl_xor(aw, 16, 64);
        ax += __shfl_xor(ax, 32, 64); ay += __shfl_xor(ay, 32, 64);
        az += __shfl_xor(az, 32, 64); aw += __shfl_xor(aw, 32, 64);
        if (grp == 0) {
            float inv = 1.0f / fmaxf((float)(b1 - b0), 1.0f);
            float4 r = make_float4(ax * inv, ay * inv, az * inv, aw * inv);
            *(float4*)(mout + (size_t)i * D + (sub << 2)) = r;
        }
    }
}

// ---------------------------------------------------------------------------
// Stage a 128-node x 64-k tile TRANSPOSED (k-major) into LDS.
// Global read: 4 consecutive rows per wave (1 KB coalesced). LDS write:
// scalar b32, stride 132 -> max 2-way bank aliasing (free).
// ---------------------------------------------------------------------------
__device__ __forceinline__ void stage_tile_T(float* __restrict__ sA,
        const float* __restrict__ g, int node_base, int N, int t) {
    int nq = t >> 4;   // 0..15
    int kq = t & 15;   // 0..15
#pragma unroll
    for (int p = 0; p < 8; ++p) {
        int node = p * 16 + nq;
        int gn = node_base + node;
        if (gn >= N) gn = N - 1;   // clamp; garbage nodes masked at store
        const float4 v = *(const float4*)(g + (size_t)gn * D + (kq << 2));
        sA[(kq * 4 + 0) * SA_STRIDE + node] = v.x;
        sA[(kq * 4 + 1) * SA_STRIDE + node] = v.y;
        sA[(kq * 4 + 2) * SA_STRIDE + node] = v.z;
        sA[(kq * 4 + 3) * SA_STRIDE + node] = v.w;
    }
}

__device__ __forceinline__ void stage_w_T(float* __restrict__ sW,
        const float* __restrict__ W, int t) {
    int cq = t >> 4;
    int kq = t & 15;
#pragma unroll
    for (int p = 0; p < 4; ++p) {
        int c = p * 16 + cq;
        const float4 v = *(const float4*)(W + c * D + (kq << 2));
        sW[(kq * 4 + 0) * SW_STRIDE + c] = v.x;
        sW[(kq * 4 + 1) * SW_STRIDE + c] = v.y;
        sW[(kq * 4 + 2) * SW_STRIDE + c] = v.z;
        sW[(kq * 4 + 3) * SW_STRIDE + c] = v.w;
    }
}

__device__ __forceinline__ void kloop(float acc[8][4],
        const float* __restrict__ sA, const float* __restrict__ sW,
        int ng, int cg) {
#pragma unroll 4
    for (int k = 0; k < 64; ++k) {
        const float4 qa0 = *(const float4*)&sA[k * SA_STRIDE + ng * 8];
        const float4 qa1 = *(const float4*)&sA[k * SA_STRIDE + ng * 8 + 4];
        const float4 qb  = *(const float4*)&sW[k * SW_STRIDE + cg * 4];
        float av[8] = {qa0.x, qa0.y, qa0.z, qa0.w, qa1.x, qa1.y, qa1.z, qa1.w};
        float bv[4] = {qb.x, qb.y, qb.z, qb.w};
#pragma unroll
        for (int i = 0; i < 8; ++i)
#pragma unroll
            for (int j = 0; j < 4; ++j)
                acc[i][j] = __builtin_fmaf(av[i], bv[j], acc[i][j]);
    }
}

// ---------------------------------------------------------------------------
// Transform: register-blocked GEMM. Block tile 128 nodes x 64 ch, thread
// tile 8x4. Two passes (mean@Wl^T then hin@Wr^T) share the LDS tiles.
// mean overwritten in place (block owns its rows). final_flag fuses the
// output head (16-lane shfl reduce), skipping the h3 write entirely.
// ---------------------------------------------------------------------------
__global__ __launch_bounds__(256) void transform_kernel(
        float* __restrict__ mean, const float* __restrict__ hin,
        const float* __restrict__ Wl, const float* __restrict__ bl,
        const float* __restrict__ Wr,
        const float* __restrict__ Wout, const float* __restrict__ bout,
        float* __restrict__ out, int N, int final_flag) {
    __shared__ float sA[64 * SA_STRIDE];
    __shared__ float sW[64 * SW_STRIDE];
    int t = threadIdx.x;
    int node_base = blockIdx.x * 128;
    int ng = t >> 4;   // node group: 8 nodes
    int cg = t & 15;   // channel group: 4 channels

    float acc[8][4];
#pragma unroll
    for (int i = 0; i < 8; ++i)
#pragma unroll
        for (int j = 0; j < 4; ++j) acc[i][j] = 0.f;

    // pass A: mean @ Wl^T
    stage_tile_T(sA, mean, node_base, N, t);
    stage_w_T(sW, Wl, t);
    __syncthreads();
    kloop(acc, sA, sW, ng, cg);
    __syncthreads();

    // pass B: hin @ Wr^T
    stage_tile_T(sA, hin, node_base, N, t);
    stage_w_T(sW, Wr, t);
    __syncthreads();
    kloop(acc, sA, sW, ng, cg);

    // epilogue
    const float4 bq = *(const float4*)&bl[cg * 4];
    const float bb[4] = {bq.x, bq.y, bq.z, bq.w};
    if (!final_flag) {
#pragma unroll
        for (int i = 0; i < 8; ++i) {
            int gn = node_base + ng * 8 + i;
            if (gn < N) {
                float4 r;
                float y0 = acc[i][0] + bb[0]; r.x = (y0 >= 0.f) ? y0 : NEG_SLOPE * y0;
                float y1 = acc[i][1] + bb[1]; r.y = (y1 >= 0.f) ? y1 : NEG_SLOPE * y1;
                float y2 = acc[i][2] + bb[2]; r.z = (y2 >= 0.f) ? y2 : NEG_SLOPE * y2;
                float y3 = acc[i][3] + bb[3]; r.w = (y3 >= 0.f) ? y3 : NEG_SLOPE * y3;
                *(float4*)(mean + (size_t)gn * D + cg * 4) = r;
            }
        }
    } else {
        const float4 wq = *(const float4*)&Wout[cg * 4];
        const float wv[4] = {wq.x, wq.y, wq.z, wq.w};
        float bo = bout[0];
#pragma unroll
        for (int i = 0; i < 8; ++i) {
            float p = 0.f;
#pragma unroll
            for (int j = 0; j < 4; ++j) {
                float y = acc[i][j] + bb[j];
                y = (y >= 0.f) ? y : NEG_SLOPE * y;
                p += y * wv[j];
            }
            p += __shfl_xor(p, 1, 64);
            p += __shfl_xor(p, 2, 64);
            p += __shfl_xor(p, 4, 64);
            p += __shfl_xor(p, 8, 64);
            if (cg == 0) {
                int gn = node_base + ng * 8 + i;
                if (gn < N) out[gn] = p + bo;
            }
        }
    }
}

extern "C" void kernel_launch(void* const* d_in, const int* in_sizes, int n_in,
                              void* d_out, int out_size, void* d_ws, size_t ws_size,
                              hipStream_t stream) {
    const float* x    = (const float*)d_in[0];
    const void*  ei   = d_in[1];
    const float* Wl1  = (const float*)d_in[2];
    const float* bl1  = (const float*)d_in[3];
    const float* Wr1  = (const float*)d_in[4];
    const float* Wl2  = (const float*)d_in[5];
    const float* bl2  = (const float*)d_in[6];
    const float* Wr2  = (const float*)d_in[7];
    const float* Wl3  = (const float*)d_in[8];
    const float* bl3  = (const float*)d_in[9];
    const float* Wr3  = (const float*)d_in[10];
    const float* Wout = (const float*)d_in[11];
    const float* bout = (const float*)d_in[12];
    float* out = (float*)d_out;

    int       N = in_sizes[0] / D;
    long long E = (long long)in_sizes[1] / 2;

    // workspace layout
    char* ws = (char*)d_ws;
    int* flag = (int*)ws;
    size_t off = 256;
    int* rowptr = (int*)(ws + off); off += (((size_t)(N + 1) * 4 + 255) / 256) * 256;
    int* blockSums = (int*)(ws + off); off += 4096;
    int* adj = (int*)(ws + off); off += (((size_t)E * 4 + 255) / 256) * 256;
    float* bufA = (float*)(ws + off); off += (size_t)N * D * 4;
    float* bufB = (float*)(ws + off);
    int* cursor = (int*)bufB;  // bufB first written in layer-2 agg; stream order => safe

    detect_kernel<<<1, 64, 0, stream>>>(ei, flag);

    // ---- CSR build (once; graph is layer-invariant) ----
    hipMemsetAsync(rowptr, 0, (size_t)(N + 1) * sizeof(int), stream);
    count_kernel<<<2048, 256, 0, stream>>>(ei, E, flag, rowptr);
    int nb = (N + SCAN_BLOCK * SCAN_ITEMS - 1) / (SCAN_BLOCK * SCAN_ITEMS);
    scan1_kernel<<<nb, SCAN_BLOCK, 0, stream>>>(rowptr, blockSums, N);
    scan2_kernel<<<1, SCAN_BLOCK, 0, stream>>>(blockSums, nb);
    scan3_kernel<<<(N + 256) / 256, 256, 0, stream>>>(rowptr, blockSums, N, (int)E);
    cursor_init_kernel<<<(N + 255) / 256, 256, 0, stream>>>(cursor, rowptr, N);
    fill_kernel<<<2048, 256, 0, stream>>>(ei, E, flag, cursor, adj);

    int tgrid = (N + 127) / 128;

    // ---- layer 1: x -> bufA ----
    agg_kernel<<<4096, 256, 0, stream>>>(x, rowptr, adj, bufA, N);
    transform_kernel<<<tgrid, 256, 0, stream>>>(bufA, x, Wl1, bl1, Wr1,
                                                Wout, bout, out, N, 0);
    // ---- layer 2: bufA -> bufB ----
    agg_kernel<<<4096, 256, 0, stream>>>(bufA, rowptr, adj, bufB, N);
    transform_kernel<<<tgrid, 256, 0, stream>>>(bufB, bufA, Wl2, bl2, Wr2,
                                                Wout, bout, out, N, 0);
    // ---- layer 3 + fused head: bufB -> out ----
    agg_kernel<<<4096, 256, 0, stream>>>(bufB, rowptr, adj, bufA, N);
    transform_kernel<<<tgrid, 256, 0, stream>>>(bufA, bufB, Wl3, bl3, Wr3,
                                                Wout, bout, out, N, 1);
}

// Round 5
// 450.304 us; speedup vs baseline: 3.9423x; 1.2907x over previous
//
#include <hip/hip_runtime.h>

#define D 64
#define NEG_SLOPE 0.01f
#define CB_SHIFT 10          // 1024 nodes per coarse bucket
#define CB_NODES 1024
#define MAXCB 128            // supports N <= 131072
#define CHUNK 8192           // edges per scatter block
#define SADJ_CAP 18432       // LDS adj stage (72 KB); mean bucket = 16384, 16 sigma
#define SA_STRIDE 132        // 128 nodes + 4 pad (k-major tile)
#define SW_STRIDE 68         // 64 ch + 4 pad

// ---------------------------------------------------------------------------
// Edge dtype detection: reference says int64, harness may hand int32.
// ---------------------------------------------------------------------------
__global__ void detect_kernel(const void* __restrict__ ei, int* __restrict__ flag) {
    int lane = threadIdx.x & 63;
    const int* p = (const int*)ei;
    int v = p[2 * lane + 1];
    unsigned long long b = __ballot(v != 0);
    if (lane == 0) *flag = (b == 0ULL) ? 1 : 0;
}

__device__ __forceinline__ int edge_at(const void* __restrict__ ei, long long idx, int is64) {
    if (is64) return (int)((const long long*)ei)[idx];
    return ((const int*)ei)[idx];
}

// ---------------------------------------------------------------------------
// Coarse histogram: per-block LDS hist of dst>>10, merged with <=128 global
// atomics per block. No per-edge global atomics.
// ---------------------------------------------------------------------------
__global__ __launch_bounds__(256) void chist_kernel(
        const void* __restrict__ ei, long long E, const int* __restrict__ flagp,
        int* __restrict__ ccount, int ncb) {
    __shared__ int hist[MAXCB];
    int t = threadIdx.x;
    if (t < MAXCB) hist[t] = 0;
    __syncthreads();
    int is64 = *flagp;
    long long tid = (long long)blockIdx.x * blockDim.x + t;
    long long nt = (long long)gridDim.x * blockDim.x;
    for (long long e = tid; e < E; e += nt) {
        int d = edge_at(ei, E + e, is64);
        atomicAdd(&hist[d >> CB_SHIFT], 1);
    }
    __syncthreads();
    if (t < ncb && hist[t]) atomicAdd(&ccount[t], hist[t]);
}

// serial scan of <=128 bucket counts; also init cursors and rowptr[N]
__global__ void cscan_kernel(const int* __restrict__ ccount, int* __restrict__ cbase,
                             int* __restrict__ ccur, int* __restrict__ rowptr,
                             int ncb, int N, int E) {
    int run = 0;
    for (int b = 0; b < ncb; ++b) {
        cbase[b] = run;
        ccur[b] = run;
        run += ccount[b];
    }
    cbase[ncb] = run;
    rowptr[N] = E;
}

// ---------------------------------------------------------------------------
// Coarse scatter: each block sorts an 8192-edge chunk into coarse-bucket order
// in LDS, reserves one contiguous global run per (block,bucket), flushes
// packed (src<<10 | dstLocal) words in ~84-edge coalesced runs.
// ---------------------------------------------------------------------------
__global__ __launch_bounds__(256) void scatter_kernel(
        const void* __restrict__ ei, long long E, const int* __restrict__ flagp,
        int* __restrict__ ccur, unsigned* __restrict__ ebuf, int ncb) {
    __shared__ int hist[MAXCB];
    __shared__ int lofs[MAXCB];
    __shared__ int gbase[MAXCB];
    __shared__ int cur[MAXCB];
    __shared__ unsigned spk[CHUNK];
    __shared__ unsigned char sbk[CHUNK];
    int t = threadIdx.x;
    if (t < MAXCB) hist[t] = 0;
    __syncthreads();
    int is64 = *flagp;
    long long start = (long long)blockIdx.x * CHUNK;
    int ccnt = (int)min((long long)CHUNK, E - start);

    // phase A: count
    for (int i = t; i < ccnt; i += 256) {
        int d = edge_at(ei, E + start + i, is64);
        atomicAdd(&hist[d >> CB_SHIFT], 1);
    }
    __syncthreads();
    if (t == 0) {
        int run = 0;
        for (int b = 0; b < ncb; ++b) { lofs[b] = run; run += hist[b]; }
    }
    if (t < ncb && hist[t]) gbase[t] = atomicAdd(&ccur[t], hist[t]);
    __syncthreads();
    if (t < ncb) cur[t] = lofs[t];
    __syncthreads();

    // phase B: LDS placement via local tickets
    for (int i = t; i < ccnt; i += 256) {
        int s = edge_at(ei, start + i, is64);
        int d = edge_at(ei, E + start + i, is64);
        int b = d >> CB_SHIFT;
        int slot = atomicAdd(&cur[b], 1);
        spk[slot] = ((unsigned)s << CB_SHIFT) | (unsigned)(d & (CB_NODES - 1));
        sbk[slot] = (unsigned char)b;
    }
    __syncthreads();

    // flush: contiguous runs per bucket
    for (int i = t; i < ccnt; i += 256) {
        int b = sbk[i];
        ebuf[gbase[b] + (i - lofs[b])] = spk[i];
    }
}

// ---------------------------------------------------------------------------
// Fine fill: one block per coarse bucket. Local per-node count + block scan
// -> rowptr; LDS ticket placement into a 72 KB adj stage; coalesced flush.
// All scattered writes stay in LDS.
// ---------------------------------------------------------------------------
__global__ __launch_bounds__(256) void finefill_kernel(
        const unsigned* __restrict__ ebuf, const int* __restrict__ cbase,
        int* __restrict__ rowptr, int* __restrict__ adj, int N) {
    __shared__ int cnt[CB_NODES];
    __shared__ int cur[CB_NODES];
    __shared__ int wpart[4];
    __shared__ int sAdj[SADJ_CAP];
    int t = threadIdx.x;
    int b = blockIdx.x;
    int e0 = cbase[b], e1 = cbase[b + 1];
    int len = e1 - e0;
    int nb = b << CB_SHIFT;

    for (int i = t; i < CB_NODES; i += 256) cnt[i] = 0;
    __syncthreads();
    for (int i = t; i < len; i += 256) {
        unsigned p = ebuf[e0 + i];
        atomicAdd(&cnt[p & (CB_NODES - 1)], 1);
    }
    __syncthreads();

    // block exclusive scan of cnt[1024]: 4 per thread + wave scan + wave partials
    int c0 = cnt[4 * t], c1 = cnt[4 * t + 1], c2 = cnt[4 * t + 2], c3 = cnt[4 * t + 3];
    int s = c0 + c1 + c2 + c3;
    int lane = t & 63, wv = t >> 6;
    int inc = s;
    for (int off = 1; off < 64; off <<= 1) {
        int u = __shfl_up(inc, off, 64);
        if (lane >= off) inc += u;
    }
    if (lane == 63) wpart[wv] = inc;
    __syncthreads();
    int wof = 0;
    for (int w = 0; w < wv; ++w) wof += wpart[w];
    int ex = wof + inc - s;
    int o0 = ex, o1 = ex + c0, o2 = o1 + c1, o3 = o2 + c2;
    cur[4 * t] = o0; cur[4 * t + 1] = o1; cur[4 * t + 2] = o2; cur[4 * t + 3] = o3;
    {
        int g = nb + 4 * t;
        if (g < N)     rowptr[g]     = e0 + o0;
        if (g + 1 < N) rowptr[g + 1] = e0 + o1;
        if (g + 2 < N) rowptr[g + 2] = e0 + o2;
        if (g + 3 < N) rowptr[g + 3] = e0 + o3;
    }
    __syncthreads();

    int big = (len > SADJ_CAP);
    for (int i = t; i < len; i += 256) {
        unsigned p = ebuf[e0 + i];
        int dl = (int)(p & (CB_NODES - 1));
        int src = (int)(p >> CB_SHIFT);
        int pos = atomicAdd(&cur[dl], 1);
        if (big) adj[e0 + pos] = src;
        else     sAdj[pos] = src;
    }
    __syncthreads();
    if (!big) {
        for (int i = t; i < len; i += 256) adj[e0 + i] = sAdj[i];
    }
}

// ---------------------------------------------------------------------------
// Gather+mean: wave per node. 16 lanes per neighbor row (float4/lane), so one
// load instruction covers 4 rows (1 KB/wave); unroll 4 -> 16 rows in flight.
// ---------------------------------------------------------------------------
__global__ __launch_bounds__(256) void agg_kernel(
        const float* __restrict__ hin, const int* __restrict__ rowptr,
        const int* __restrict__ adj, float* __restrict__ mout, int N) {
    int lane = threadIdx.x & 63;
    int sub = lane & 15;      // float4 slot within row
    int grp = lane >> 4;      // which of 4 concurrent rows
    int wid = blockIdx.x * (blockDim.x >> 6) + (threadIdx.x >> 6);
    int nw = gridDim.x * (blockDim.x >> 6);

    for (int i = wid; i < N; i += nw) {
        int b0 = rowptr[i], b1 = rowptr[i + 1];
        float ax = 0.f, ay = 0.f, az = 0.f, aw = 0.f;
        for (int base = b0; base < b1; base += 64) {
            int idx = base + lane;
            int sl = (idx < b1) ? adj[idx] : 0;   // coalesced adj chunk
            int cnt = min(64, b1 - base);
            int nq = (cnt + 3) >> 2;
#pragma unroll 4
            for (int t = 0; t < nq; ++t) {
                int j = (t << 2) + grp;
                int s = __shfl(sl, j, 64);
                if (j < cnt) {
                    const float4 v = *(const float4*)(hin + (size_t)s * D + (sub << 2));
                    ax += v.x; ay += v.y; az += v.z; aw += v.w;
                }
            }
        }
        ax += __shfl_xor(ax, 16, 64); ay += __shfl_xor(ay, 16, 64);
        az += __shfl_xor(az, 16, 64); aw += __shfl_xor(aw, 16, 64);
        ax += __shfl_xor(ax, 32, 64); ay += __shfl_xor(ay, 32, 64);
        az += __shfl_xor(az, 32, 64); aw += __shfl_xor(aw, 32, 64);
        if (grp == 0) {
            float inv = 1.0f / fmaxf((float)(b1 - b0), 1.0f);
            float4 r = make_float4(ax * inv, ay * inv, az * inv, aw * inv);
            *(float4*)(mout + (size_t)i * D + (sub << 2)) = r;
        }
    }
}

// ---------------------------------------------------------------------------
// Stage a 128-node x 64-k tile TRANSPOSED (k-major) into LDS.
// ---------------------------------------------------------------------------
__device__ __forceinline__ void stage_tile_T(float* __restrict__ sA,
        const float* __restrict__ g, int node_base, int N, int t) {
    int nq = t >> 4;   // 0..15
    int kq = t & 15;   // 0..15
#pragma unroll
    for (int p = 0; p < 8; ++p) {
        int node = p * 16 + nq;
        int gn = node_base + node;
        if (gn >= N) gn = N - 1;   // clamp; garbage nodes masked at store
        const float4 v = *(const float4*)(g + (size_t)gn * D + (kq << 2));
        sA[(kq * 4 + 0) * SA_STRIDE + node] = v.x;
        sA[(kq * 4 + 1) * SA_STRIDE + node] = v.y;
        sA[(kq * 4 + 2) * SA_STRIDE + node] = v.z;
        sA[(kq * 4 + 3) * SA_STRIDE + node] = v.w;
    }
}

__device__ __forceinline__ void stage_w_T(float* __restrict__ sW,
        const float* __restrict__ W, int t) {
    int cq = t >> 4;
    int kq = t & 15;
#pragma unroll
    for (int p = 0; p < 4; ++p) {
        int c = p * 16 + cq;
        const float4 v = *(const float4*)(W + c * D + (kq << 2));
        sW[(kq * 4 + 0) * SW_STRIDE + c] = v.x;
        sW[(kq * 4 + 1) * SW_STRIDE + c] = v.y;
        sW[(kq * 4 + 2) * SW_STRIDE + c] = v.z;
        sW[(kq * 4 + 3) * SW_STRIDE + c] = v.w;
    }
}

__device__ __forceinline__ void kloop(float acc[8][4],
        const float* __restrict__ sA, const float* __restrict__ sW,
        int ng, int cg) {
#pragma unroll 4
    for (int k = 0; k < 64; ++k) {
        const float4 qa0 = *(const float4*)&sA[k * SA_STRIDE + ng * 8];
        const float4 qa1 = *(const float4*)&sA[k * SA_STRIDE + ng * 8 + 4];
        const float4 qb  = *(const float4*)&sW[k * SW_STRIDE + cg * 4];
        float av[8] = {qa0.x, qa0.y, qa0.z, qa0.w, qa1.x, qa1.y, qa1.z, qa1.w};
        float bv[4] = {qb.x, qb.y, qb.z, qb.w};
#pragma unroll
        for (int i = 0; i < 8; ++i)
#pragma unroll
            for (int j = 0; j < 4; ++j)
                acc[i][j] = __builtin_fmaf(av[i], bv[j], acc[i][j]);
    }
}

// ---------------------------------------------------------------------------
// Transform: register-blocked GEMM. Block tile 128 nodes x 64 ch, thread
// tile 8x4. final_flag fuses the output head.
// ---------------------------------------------------------------------------
__global__ __launch_bounds__(256) void transform_kernel(
        float* __restrict__ mean, const float* __restrict__ hin,
        const float* __restrict__ Wl, const float* __restrict__ bl,
        const float* __restrict__ Wr,
        const float* __restrict__ Wout, const float* __restrict__ bout,
        float* __restrict__ out, int N, int final_flag) {
    __shared__ float sA[64 * SA_STRIDE];
    __shared__ float sW[64 * SW_STRIDE];
    int t = threadIdx.x;
    int node_base = blockIdx.x * 128;
    int ng = t >> 4;   // node group: 8 nodes
    int cg = t & 15;   // channel group: 4 channels

    float acc[8][4];
#pragma unroll
    for (int i = 0; i < 8; ++i)
#pragma unroll
        for (int j = 0; j < 4; ++j) acc[i][j] = 0.f;

    // pass A: mean @ Wl^T
    stage_tile_T(sA, mean, node_base, N, t);
    stage_w_T(sW, Wl, t);
    __syncthreads();
    kloop(acc, sA, sW, ng, cg);
    __syncthreads();

    // pass B: hin @ Wr^T
    stage_tile_T(sA, hin, node_base, N, t);
    stage_w_T(sW, Wr, t);
    __syncthreads();
    kloop(acc, sA, sW, ng, cg);

    // epilogue
    const float4 bq = *(const float4*)&bl[cg * 4];
    const float bb[4] = {bq.x, bq.y, bq.z, bq.w};
    if (!final_flag) {
#pragma unroll
        for (int i = 0; i < 8; ++i) {
            int gn = node_base + ng * 8 + i;
            if (gn < N) {
                float4 r;
                float y0 = acc[i][0] + bb[0]; r.x = (y0 >= 0.f) ? y0 : NEG_SLOPE * y0;
                float y1 = acc[i][1] + bb[1]; r.y = (y1 >= 0.f) ? y1 : NEG_SLOPE * y1;
                float y2 = acc[i][2] + bb[2]; r.z = (y2 >= 0.f) ? y2 : NEG_SLOPE * y2;
                float y3 = acc[i][3] + bb[3]; r.w = (y3 >= 0.f) ? y3 : NEG_SLOPE * y3;
                *(float4*)(mean + (size_t)gn * D + cg * 4) = r;
            }
        }
    } else {
        const float4 wq = *(const float4*)&Wout[cg * 4];
        const float wv[4] = {wq.x, wq.y, wq.z, wq.w};
        float bo = bout[0];
#pragma unroll
        for (int i = 0; i < 8; ++i) {
            float p = 0.f;
#pragma unroll
            for (int j = 0; j < 4; ++j) {
                float y = acc[i][j] + bb[j];
                y = (y >= 0.f) ? y : NEG_SLOPE * y;
                p += y * wv[j];
            }
            p += __shfl_xor(p, 1, 64);
            p += __shfl_xor(p, 2, 64);
            p += __shfl_xor(p, 4, 64);
            p += __shfl_xor(p, 8, 64);
            if (cg == 0) {
                int gn = node_base + ng * 8 + i;
                if (gn < N) out[gn] = p + bo;
            }
        }
    }
}

extern "C" void kernel_launch(void* const* d_in, const int* in_sizes, int n_in,
                              void* d_out, int out_size, void* d_ws, size_t ws_size,
                              hipStream_t stream) {
    const float* x    = (const float*)d_in[0];
    const void*  ei   = d_in[1];
    const float* Wl1  = (const float*)d_in[2];
    const float* bl1  = (const float*)d_in[3];
    const float* Wr1  = (const float*)d_in[4];
    const float* Wl2  = (const float*)d_in[5];
    const float* bl2  = (const float*)d_in[6];
    const float* Wr2  = (const float*)d_in[7];
    const float* Wl3  = (const float*)d_in[8];
    const float* bl3  = (const float*)d_in[9];
    const float* Wr3  = (const float*)d_in[10];
    const float* Wout = (const float*)d_in[11];
    const float* bout = (const float*)d_in[12];
    float* out = (float*)d_out;

    int       N = in_sizes[0] / D;
    long long E = (long long)in_sizes[1] / 2;
    int ncb = (N + CB_NODES - 1) >> CB_SHIFT;   // <= MAXCB for N <= 131072

    // workspace layout
    char* ws = (char*)d_ws;
    int* flag = (int*)ws;
    size_t off = 256;
    int* ccount = (int*)(ws + off); off += 512;    // MAXCB ints
    int* cbase  = (int*)(ws + off); off += 1024;   // MAXCB+1 ints
    int* ccur   = (int*)(ws + off); off += 512;    // MAXCB ints
    int* rowptr = (int*)(ws + off); off += (((size_t)(N + 1) * 4 + 255) / 256) * 256;
    int* adj    = (int*)(ws + off); off += (((size_t)E * 4 + 255) / 256) * 256;
    float* bufA = (float*)(ws + off); off += (size_t)N * D * 4;
    float* bufB = (float*)(ws + off);
    unsigned* ebuf = (unsigned*)bufB;  // consumed by finefill before bufB's first write

    detect_kernel<<<1, 64, 0, stream>>>(ei, flag);

    // ---- CSR build via two-level counting sort (once; graph layer-invariant) ----
    hipMemsetAsync(ccount, 0, 512, stream);
    chist_kernel<<<256, 256, 0, stream>>>(ei, E, flag, ccount, ncb);
    cscan_kernel<<<1, 1, 0, stream>>>(ccount, cbase, ccur, rowptr, ncb, N, (int)E);
    int sgrid = (int)((E + CHUNK - 1) / CHUNK);
    scatter_kernel<<<sgrid, 256, 0, stream>>>(ei, E, flag, ccur, ebuf, ncb);
    finefill_kernel<<<ncb, 256, 0, stream>>>(ebuf, cbase, rowptr, adj, N);

    int tgrid = (N + 127) / 128;

    // ---- layer 1: x -> bufA ----
    agg_kernel<<<4096, 256, 0, stream>>>(x, rowptr, adj, bufA, N);
    transform_kernel<<<tgrid, 256, 0, stream>>>(bufA, x, Wl1, bl1, Wr1,
                                                Wout, bout, out, N, 0);
    // ---- layer 2: bufA -> bufB ----
    agg_kernel<<<4096, 256, 0, stream>>>(bufA, rowptr, adj, bufB, N);
    transform_kernel<<<tgrid, 256, 0, stream>>>(bufB, bufA, Wl2, bl2, Wr2,
                                                Wout, bout, out, N, 0);
    // ---- layer 3 + fused head: bufB -> out ----
    agg_kernel<<<4096, 256, 0, stream>>>(bufB, rowptr, adj, bufA, N);
    transform_kernel<<<tgrid, 256, 0, stream>>>(bufA, bufB, Wl3, bl3, Wr3,
                                                Wout, bout, out, N, 1);
}